// Round 4
// baseline (7810.846 us; speedup 1.0000x reference)
//
#include <hip/hip_runtime.h>

// ---------------------------------------------------------------------------
// SequenceTaggle: hierarchical GRU (sentence enc -> doc enc) on MI355X.
// V=32000 E=256 H=256 O=2 S=96 T=32 B=32, N = S*B = 3072.
// DEVICE DTYPES: float tensors f32; tokens int32; output f32.
// Internal: bf16 MFMA, f32 accumulation. Weights converted once per launch.
// Doc encoder: persistent single-workgroup kernels (h lives in LDS), with
// input projections (xW+bi) precomputed by parallel GEMMs.
// ---------------------------------------------------------------------------

typedef __bf16 bf16;
typedef __bf16 bf16x8 __attribute__((ext_vector_type(8)));
typedef __bf16 bf16x4 __attribute__((ext_vector_type(4)));
typedef float  f32x4  __attribute__((ext_vector_type(4)));

static __device__ __forceinline__ f32x4 mfma16(bf16x8 a, bf16x8 b, f32x4 c) {
  // A: lane row = lane&15, k = (lane>>4)*8 + j ; B: lane col = lane&15, same k
  // D: col = lane&15, row = (lane>>4)*4 + reg   [verified m89/m91 layout]
  return __builtin_amdgcn_mfma_f32_16x16x32_bf16(a, b, c, 0, 0, 0);
}
static __device__ __forceinline__ float sigm(float x) { return 1.f / (1.f + __expf(-x)); }

// ---- one-shot weight conversion: 12 GRU mats (196608 ea) + linW (131072) ----
__global__ __launch_bounds__(256) void conv13(
    const float* s0, const float* s1, const float* s2, const float* s3,
    const float* s4, const float* s5, const float* s6, const float* s7,
    const float* s8, const float* s9, const float* s10, const float* s11,
    const float* s12, bf16* __restrict__ dst)
{
  const float* srcs[13] = {s0,s1,s2,s3,s4,s5,s6,s7,s8,s9,s10,s11,s12};
  int m = blockIdx.y;
  int n4 = (m == 12) ? 32768 : 49152;
  int i = blockIdx.x * 256 + threadIdx.x;
  if (i >= n4) return;
  float4 v = ((const float4*)srcs[m])[i];
  bf16x4 o;
  o[0] = (bf16)v.x; o[1] = (bf16)v.y; o[2] = (bf16)v.z; o[3] = (bf16)v.w;
  ((bf16x4*)(dst + (size_t)m * 196608))[i] = o;
}

// ---------------------------------------------------------------------------
// Fused GRU step (sentence encoder). Same as round 3 (verified).
// ---------------------------------------------------------------------------
__global__ __launch_bounds__(256) void gru_step(
    const bf16* __restrict__ xF, const bf16* __restrict__ hpF, bf16* __restrict__ hoF,
    const bf16* __restrict__ WiF, const bf16* __restrict__ WhF,
    const float* __restrict__ biF, const float* __restrict__ bhF,
    const bf16* __restrict__ xB, const bf16* __restrict__ hpB, bf16* __restrict__ hoB,
    const bf16* __restrict__ WiB, const bf16* __restrict__ WhB,
    const float* __restrict__ biB, const float* __restrict__ bhB,
    const int* __restrict__ tok, const float* __restrict__ emb, int t, int hstride)
{
  const bf16 *x, *hp, *Wi, *Wh;
  const float *bi, *bh;
  bf16* ho;
  if (blockIdx.y == 0) { x = xF; hp = hpF; ho = hoF; Wi = WiF; Wh = WhF; bi = biF; bh = bhF; }
  else                 { x = xB; hp = hpB; ho = hoB; Wi = WiB; Wh = WhB; bi = biB; bh = bhB; }

  int wave = (threadIdx.x >> 6) + (blockIdx.x << 2);
  int cj   = (wave & 15) << 4;
  int m0   = (wave >> 4) << 4;
  int lane = threadIdx.x & 63;
  int r16  = lane & 15, g4 = lane >> 4;
  int arow = m0 + r16;

  const bf16* wi = Wi + (size_t)(cj + r16) * 256;
  const bf16* wh = Wh + (size_t)(cj + r16) * 256;

  f32x4 ax0 = {0,0,0,0}, ax1 = {0,0,0,0}, ax2 = {0,0,0,0};
  f32x4 ah0 = {0,0,0,0}, ah1 = {0,0,0,0}, ah2 = {0,0,0,0};

  if (x) {
    const bf16* xp = x + (size_t)arow * 256;
#pragma unroll
    for (int kk = 0; kk < 8; kk++) {
      int k0 = kk * 32 + g4 * 8;
      bf16x8 a = *(const bf16x8*)(xp + k0);
      ax0 = mfma16(a, *(const bf16x8*)(wi + k0),          ax0);
      ax1 = mfma16(a, *(const bf16x8*)(wi + 65536 + k0),  ax1);
      ax2 = mfma16(a, *(const bf16x8*)(wi + 131072 + k0), ax2);
    }
  } else {
    int tokid = tok[((arow >> 5) << 10) + (t << 5) + (arow & 31)];
    const float* ep = emb + (size_t)tokid * 256;
#pragma unroll
    for (int kk = 0; kk < 8; kk++) {
      int k0 = kk * 32 + g4 * 8;
      float4 u = *(const float4*)(ep + k0);
      float4 w = *(const float4*)(ep + k0 + 4);
      bf16x8 a;
      a[0] = (bf16)u.x; a[1] = (bf16)u.y; a[2] = (bf16)u.z; a[3] = (bf16)u.w;
      a[4] = (bf16)w.x; a[5] = (bf16)w.y; a[6] = (bf16)w.z; a[7] = (bf16)w.w;
      ax0 = mfma16(a, *(const bf16x8*)(wi + k0),          ax0);
      ax1 = mfma16(a, *(const bf16x8*)(wi + 65536 + k0),  ax1);
      ax2 = mfma16(a, *(const bf16x8*)(wi + 131072 + k0), ax2);
    }
  }
  if (hp) {
    const bf16* hap = hp + (size_t)arow * hstride;
#pragma unroll
    for (int kk = 0; kk < 8; kk++) {
      int k0 = kk * 32 + g4 * 8;
      bf16x8 a = *(const bf16x8*)(hap + k0);
      ah0 = mfma16(a, *(const bf16x8*)(wh + k0),          ah0);
      ah1 = mfma16(a, *(const bf16x8*)(wh + 65536 + k0),  ah1);
      ah2 = mfma16(a, *(const bf16x8*)(wh + 131072 + k0), ah2);
    }
  }

  float bir = bi[cj + r16], biz = bi[256 + cj + r16], bin = bi[512 + cj + r16];
  float bhr = bh[cj + r16], bhz = bh[256 + cj + r16], bhn = bh[512 + cj + r16];

#pragma unroll
  for (int rg = 0; rg < 4; rg++) {
    int orow = m0 + g4 * 4 + rg;
    float r = sigm(ax0[rg] + bir + ah0[rg] + bhr);
    float z = sigm(ax1[rg] + biz + ah1[rg] + bhz);
    float n = tanhf(ax2[rg] + bin + r * (ah2[rg] + bhn));
    float hpv = hp ? (float)hp[(size_t)orow * hstride + cj + r16] : 0.f;
    float hv = (1.f - z) * n + z * hpv;
    ho[(size_t)orow * hstride + cj + r16] = (bf16)hv;
  }
}

// ---------------------------------------------------------------------------
// Row LayerNorm in place (bf16 data, f32 params), wave per row. D in {256,512}.
// ---------------------------------------------------------------------------
__global__ __launch_bounds__(256) void ln_rows(
    bf16* __restrict__ data, const float* __restrict__ gam, const float* __restrict__ bet,
    int rows, int D)
{
  int wid = threadIdx.x >> 6, lane = threadIdx.x & 63;
  int row = (blockIdx.x << 2) + wid;
  if (row >= rows) return;
  bf16* p = data + (size_t)row * D;
  int c = D >> 6;
  float v[8];
  float s = 0.f;
  if (c == 8) {
    bf16x8 t8 = *(const bf16x8*)(p + lane * 8);
#pragma unroll
    for (int j = 0; j < 8; j++) { v[j] = (float)t8[j]; s += v[j]; }
  } else {
    bf16x4 t4 = *(const bf16x4*)(p + lane * 4);
#pragma unroll
    for (int j = 0; j < 4; j++) { v[j] = (float)t4[j]; s += v[j]; }
#pragma unroll
    for (int j = 4; j < 8; j++) v[j] = 0.f;
  }
  float sq = 0.f;
  for (int j = 0; j < c; j++) sq += v[j] * v[j];
  for (int m = 32; m; m >>= 1) { s += __shfl_xor(s, m); sq += __shfl_xor(sq, m); }
  float invD = 1.f / (float)D;
  float mu  = s * invD;
  float var = sq * invD - mu * mu;
  float inv = rsqrtf(fmaxf(var, 0.f) + 1e-5f);
  int base = lane * c;
  for (int j = 0; j < c; j++) {
    float o = (v[j] - mu) * inv * gam[base + j] + bet[base + j];
    p[base + j] = (bf16)o;
  }
}

// ---------------------------------------------------------------------------
// Fused sentence tail (unchanged from round 3, verified).
// ---------------------------------------------------------------------------
__global__ __launch_bounds__(256) void sent_tail(
    const bf16* __restrict__ hf, const bf16* __restrict__ hb,
    const float* __restrict__ gam, const float* __restrict__ bet,
    const bf16* __restrict__ W, const float* __restrict__ bias,
    bf16* __restrict__ store, int c, int row_base)
{
  int wave = threadIdx.x >> 6;
  int lane = threadIdx.x & 63;
  int r16 = lane & 15, g4 = lane >> 4;
  int r0 = (int)blockIdx.x << 4;
  size_t rowoff = (size_t)(r0 + r16) * 256;

  f32x4 ms0 = {0,0,0,0}, ms1 = {0,0,0,0}, ms2 = {0,0,0,0}, ms3 = {0,0,0,0};

  for (int t = 0; t < 32; t++) {
    const bf16* pf = hf + (size_t)t * c * 256 + rowoff;
    const bf16* pb = hb + (size_t)t * c * 256 + rowoff;
    bf16x8 xv[16];
    float s = 0.f, sq = 0.f;
#pragma unroll
    for (int kk = 0; kk < 16; kk++) {
      int k0 = kk * 32 + g4 * 8;
      xv[kk] = (kk < 8) ? *(const bf16x8*)(pf + k0) : *(const bf16x8*)(pb + k0 - 256);
#pragma unroll
      for (int j = 0; j < 8; j++) { float f = (float)xv[kk][j]; s += f; sq += f * f; }
    }
    s  += __shfl_xor(s, 16);  s  += __shfl_xor(s, 32);
    sq += __shfl_xor(sq, 16); sq += __shfl_xor(sq, 32);
    float mu  = s * (1.f / 512.f);
    float var = sq * (1.f / 512.f) - mu * mu;
    float inv = rsqrtf(fmaxf(var, 0.f) + 1e-5f);
#pragma unroll
    for (int kk = 0; kk < 16; kk++) {
      int k0 = kk * 32 + g4 * 8;
      float ga[8], be[8];
      *(float4*)(ga)     = *(const float4*)(gam + k0);
      *(float4*)(ga + 4) = *(const float4*)(gam + k0 + 4);
      *(float4*)(be)     = *(const float4*)(bet + k0);
      *(float4*)(be + 4) = *(const float4*)(bet + k0 + 4);
#pragma unroll
      for (int j = 0; j < 8; j++)
        xv[kk][j] = (bf16)(((float)xv[kk][j] - mu) * inv * ga[j] + be[j]);
    }
#pragma unroll
    for (int tc = 0; tc < 4; tc++) {
      int cj = wave * 64 + tc * 16;
      const bf16* wp = W + (size_t)(cj + r16) * 512;
      f32x4 acc = {0,0,0,0};
#pragma unroll
      for (int kk = 0; kk < 16; kk++)
        acc = mfma16(xv[kk], *(const bf16x8*)(wp + kk * 32 + g4 * 8), acc);
      float bb = bias[cj + r16];
      f32x4* msp = (tc == 0) ? &ms0 : (tc == 1) ? &ms1 : (tc == 2) ? &ms2 : &ms3;
#pragma unroll
      for (int j = 0; j < 4; j++) (*msp)[j] += tanhf(acc[j] + bb);
    }
  }
#pragma unroll
  for (int tc = 0; tc < 4; tc++) {
    int cj = wave * 64 + tc * 16;
    f32x4 ms = (tc == 0) ? ms0 : (tc == 1) ? ms1 : (tc == 2) ? ms2 : ms3;
#pragma unroll
    for (int j = 0; j < 4; j++) {
      int row = row_base + r0 + g4 * 4 + j;
      store[(size_t)row * 256 + cj + r16] = (bf16)(ms[j] * 0.03125f);
    }
  }
}

// ---------------------------------------------------------------------------
// xw = X(M x 256 bf16) @ W(768 x 256 bf16)^T + bias(f32) -> (M x 768) f32.
// gridDim.y selects (W0,b0,o0) / (W1,b1,o1). blocks = M/16*48/4.
// ---------------------------------------------------------------------------
__global__ __launch_bounds__(256) void xw_gemm(
    const bf16* __restrict__ X,
    const bf16* __restrict__ W0, const float* __restrict__ b0, float* __restrict__ o0,
    const bf16* __restrict__ W1, const float* __restrict__ b1, float* __restrict__ o1)
{
  const bf16* W = blockIdx.y ? W1 : W0;
  const float* bias = blockIdx.y ? b1 : b0;
  float* out = blockIdx.y ? o1 : o0;
  int wave = (int)blockIdx.x * 4 + (threadIdx.x >> 6);
  int rt = wave / 48, ct = wave - rt * 48;
  int lane = threadIdx.x & 63;
  int r16 = lane & 15, g4 = lane >> 4;
  const bf16* ap = X + (size_t)(rt * 16 + r16) * 256;
  const bf16* wp = W + (size_t)(ct * 16 + r16) * 256;
  f32x4 acc = {0,0,0,0};
#pragma unroll
  for (int kk = 0; kk < 8; kk++) {
    int k0 = kk * 32 + g4 * 8;
    acc = mfma16(*(const bf16x8*)(ap + k0), *(const bf16x8*)(wp + k0), acc);
  }
  float bv = bias[ct * 16 + r16];
#pragma unroll
  for (int j = 0; j < 4; j++)
    out[(size_t)(rt * 16 + g4 * 4 + j) * 768 + ct * 16 + r16] = acc[j] + bv;
}

// ---------------------------------------------------------------------------
// Persistent doc GRU: one workgroup (1024 thr = 16 waves) per direction; h
// (32x256) lives in LDS across all S steps. Per step: h@Wh via MFMA (96 tiles,
// 6/wave), gates with precomputed xw, optional fused LN on the y output.
// blockIdx.x = 0 -> fwd params/dir, 1 -> bwd (writes col base 256).
// ---------------------------------------------------------------------------
__global__ __launch_bounds__(1024) void doc_gru(
    const float* __restrict__ xwF, const bf16* __restrict__ WhF_, const float* __restrict__ bhF_,
    const float* __restrict__ xwB, const bf16* __restrict__ WhB_, const float* __restrict__ bhB_,
    bf16* __restrict__ yout, int ostride,
    const float* __restrict__ lng, const float* __restrict__ lnb, int S)
{
  int dir = blockIdx.x;
  const float* xw = dir ? xwB : xwF;
  const bf16*  Wh = dir ? WhB_ : WhF_;
  const float* bh = dir ? bhB_ : bhF_;
  int obase = dir ? 256 : 0;

  __shared__ bf16 hbuf[32][256];
  {
    bf16x8 z = {};
    ((bf16x8*)hbuf)[threadIdx.x] = z;   // 1024 * 8 = 8192 elems
  }
  __syncthreads();

  int w = threadIdx.x >> 6, lane = threadIdx.x & 63;
  int r16 = lane & 15, g4 = lane >> 4;
  int rt = w & 1, htb = w >> 1;

  for (int i = 0; i < S; i++) {
    int st = dir ? (S - 1 - i) : i;
    bf16x8 a[8];
#pragma unroll
    for (int kk = 0; kk < 8; kk++)
      a[kk] = *(const bf16x8*)&hbuf[rt * 16 + r16][kk * 32 + g4 * 8];
    float hnew[2][4];
    const float* xp = xw + (size_t)st * 32 * 768;
#pragma unroll
    for (int hs = 0; hs < 2; hs++) {
      int c = (htb + hs * 8) * 16 + r16;
      const bf16* wh = Wh + (size_t)c * 256;
      f32x4 A0 = {0,0,0,0}, A1 = {0,0,0,0}, A2 = {0,0,0,0};
#pragma unroll
      for (int kk = 0; kk < 8; kk++) {
        int k0 = kk * 32 + g4 * 8;
        A0 = mfma16(a[kk], *(const bf16x8*)(wh + k0),          A0);
        A1 = mfma16(a[kk], *(const bf16x8*)(wh + 65536 + k0),  A1);
        A2 = mfma16(a[kk], *(const bf16x8*)(wh + 131072 + k0), A2);
      }
      float bhr = bh[c], bhz = bh[c + 256], bhn = bh[c + 512];
#pragma unroll
      for (int j = 0; j < 4; j++) {
        int m = rt * 16 + g4 * 4 + j;
        const float* xr = xp + (size_t)m * 768 + c;
        float r = sigm(xr[0]   + A0[j] + bhr);
        float z = sigm(xr[256] + A1[j] + bhz);
        float n = tanhf(xr[512] + r * (A2[j] + bhn));
        float hp = (float)hbuf[m][c];
        hnew[hs][j] = (1.f - z) * n + z * hp;
      }
    }
    __syncthreads();               // all reads of hbuf for this step done
#pragma unroll
    for (int hs = 0; hs < 2; hs++) {
      int c = (htb + hs * 8) * 16 + r16;
#pragma unroll
      for (int j = 0; j < 4; j++)
        hbuf[rt * 16 + g4 * 4 + j][c] = (bf16)hnew[hs][j];
    }
    __syncthreads();               // hbuf updated
    if (lng) {
      // fused LN(256) on y; recurrence uses raw h in hbuf. wave -> 2 rows.
#pragma unroll
      for (int rr = 0; rr < 2; rr++) {
        int row = w * 2 + rr;
        bf16x4 v4 = *(const bf16x4*)&hbuf[row][lane * 4];
        float v[4]; float sm = 0.f, sq = 0.f;
#pragma unroll
        for (int j = 0; j < 4; j++) { v[j] = (float)v4[j]; sm += v[j]; sq += v[j] * v[j]; }
        for (int msk = 32; msk; msk >>= 1) { sm += __shfl_xor(sm, msk); sq += __shfl_xor(sq, msk); }
        float mu  = sm * (1.f / 256.f);
        float var = sq * (1.f / 256.f) - mu * mu;
        float inv = rsqrtf(fmaxf(var, 0.f) + 1e-5f);
        bf16x4 o;
#pragma unroll
        for (int j = 0; j < 4; j++)
          o[j] = (bf16)((v[j] - mu) * inv * lng[lane * 4 + j] + lnb[lane * 4 + j]);
        *(bf16x4*)&yout[((size_t)st * 32 + row) * ostride + lane * 4] = o;
      }
    } else {
#pragma unroll
      for (int hs = 0; hs < 2; hs++) {
        int c = (htb + hs * 8) * 16 + r16;
#pragma unroll
        for (int j = 0; j < 4; j++)
          yout[((size_t)st * 32 + rt * 16 + g4 * 4 + j) * ostride + obase + c] = (bf16)hnew[hs][j];
      }
    }
  }
}

// ---------------------------------------------------------------------------
// Fused LN(512) + sigmoid head: out(3072x2 f32). Wave per row.
// ---------------------------------------------------------------------------
__global__ __launch_bounds__(256) void ln_out_head(
    const bf16* __restrict__ X, const float* __restrict__ lng, const float* __restrict__ lnb,
    const float* __restrict__ W, const float* __restrict__ bias, float* __restrict__ out)
{
  int w = threadIdx.x >> 6, lane = threadIdx.x & 63;
  int row = (int)blockIdx.x * 4 + w;
  bf16x8 v8 = *(const bf16x8*)&X[(size_t)row * 512 + lane * 8];
  float v[8]; float sm = 0.f, sq = 0.f;
#pragma unroll
  for (int j = 0; j < 8; j++) { v[j] = (float)v8[j]; sm += v[j]; sq += v[j] * v[j]; }
  for (int msk = 32; msk; msk >>= 1) { sm += __shfl_xor(sm, msk); sq += __shfl_xor(sq, msk); }
  float mu  = sm * (1.f / 512.f);
  float var = sq * (1.f / 512.f) - mu * mu;
  float inv = rsqrtf(fmaxf(var, 0.f) + 1e-5f);
  float a0 = 0.f, a1 = 0.f;
  int base = lane * 8;
#pragma unroll
  for (int j = 0; j < 8; j++) {
    float y = (v[j] - mu) * inv * lng[base + j] + lnb[base + j];
    a0 += y * W[base + j];
    a1 += y * W[512 + base + j];
  }
  for (int msk = 32; msk; msk >>= 1) { a0 += __shfl_xor(a0, msk); a1 += __shfl_xor(a1, msk); }
  if (lane == 0) {
    out[(size_t)row * 2 + 0] = sigm(a0 + bias[0]);
    out[(size_t)row * 2 + 1] = sigm(a1 + bias[1]);
  }
}

// ---------------------------------------------------------------------------
extern "C" void kernel_launch(void* const* d_in, const int* in_sizes, int n_in,
                              void* d_out, int out_size, void* d_ws, size_t ws_size,
                              hipStream_t stream)
{
  (void)in_sizes; (void)n_in; (void)out_size;
  const int*   tokens = (const int*)d_in[0];
  const float* emb    = (const float*)d_in[1];
  auto fp = [&](int i) { return (const float*)d_in[i]; };
  const float *s_WiF = fp(2),  *s_WhF = fp(3),  *s_biF = fp(4),  *s_bhF = fp(5);
  const float *s_lnF_g = fp(6), *s_lnF_b = fp(7);
  const float *s_Wi_f = fp(8),  *s_Wh_f = fp(9),  *s_bi_f = fp(10), *s_bh_f = fp(11);
  const float *s_Wi_b = fp(12), *s_Wh_b = fp(13), *s_bi_b = fp(14), *s_bh_b = fp(15);
  const float *s_ln_g = fp(16), *s_ln_b = fp(17), *s_linW = fp(18), *s_linb = fp(19);
  const float *dWiF = fp(20), *dWhF = fp(21), *dbiF = fp(22), *dbhF = fp(23);
  const float *d_lnF_g = fp(24), *d_lnF_b = fp(25);
  const float *dWi_f = fp(26), *dWh_f = fp(27), *dbi_f = fp(28), *dbh_f = fp(29);
  const float *dWi_b = fp(30), *dWh_b = fp(31), *dbi_b = fp(32), *dbh_b = fp(33);
  const float *d_ln_g = fp(34), *d_ln_b = fp(35), *out_W = fp(36), *out_b = fp(37);

  const int T = 32, S = 96;
  const int GW = 196608;           // 768*256 elems per GRU weight matrix

  // ---- converted bf16 weights ----
  bf16* wc = (bf16*)d_ws;
  bf16 *c_sWiF = wc,         *c_sWhF = wc + GW;
  bf16 *c_sWif = wc + 2*GW,  *c_sWhf = wc + 3*GW;
  bf16 *c_sWib = wc + 4*GW,  *c_sWhb = wc + 5*GW;
  bf16 *c_dWiF = wc + 6*GW,  *c_dWhF = wc + 7*GW;
  bf16 *c_dWif = wc + 8*GW,  *c_dWhf = wc + 9*GW;
  bf16 *c_dWib = wc + 10*GW, *c_dWhb = wc + 11*GW;
  bf16 *c_linW = wc + 12*GW;
  const size_t WB = (size_t)(12 * GW + 131072) * 2;   // 4,980,736 B

  conv13<<<dim3(192, 13), 256, 0, stream>>>(
      s_WiF, s_WhF, s_Wi_f, s_Wh_f, s_Wi_b, s_Wh_b,
      dWiF, dWhF, dWi_f, dWh_f, dWi_b, dWh_b, s_linW, wc);

  // ---- fixed workspace: xw buffers (f32) + doc buffers ----
  char* ws = (char*)d_ws + WB;
  float* xw_u = (float*)ws;                       // (3072, 768)
  float* xw_f = xw_u + (size_t)3072 * 768;
  float* xw_b = xw_f + (size_t)3072 * 768;
  bf16* store = (bf16*)(xw_b + (size_t)3072 * 768);  // (3072, 256)
  bf16* yd1ln = store + (size_t)3072 * 256;          // (3072, 256) LN'd
  bf16* ybid  = yd1ln + (size_t)3072 * 256;          // (3072, 512) f|b
  const size_t fixedB = WB + (size_t)3 * 3072 * 768 * 4
                      + ((size_t)3072 * 256 + 3072 * 256 + 3072 * 512) * 2;

  // ---- sentence chunk size (rows; multiple of 32 = whole sentences) ----
  int c = 3072;
  while (c > 96 && fixedB + (size_t)3 * T * c * 512 > ws_size) c >>= 1;
  bf16* y1 = (bf16*)((char*)d_ws + fixedB);       // (T, c, 256)
  bf16* hf = y1 + (size_t)T * c * 256;
  bf16* hb = hf + (size_t)T * c * 256;
  const size_t cH = (size_t)c * 256;

  // ---- sentence encoder, chunked ----
  for (int base = 0; base < 3072; base += c) {
    const int* tkb = tokens + (size_t)base * 32;
    for (int t = 0; t < T; t++) {
      gru_step<<<dim3(c / 4, 1), 256, 0, stream>>>(
          nullptr, t ? y1 + (size_t)(t - 1) * cH : nullptr, y1 + (size_t)t * cH,
          c_sWiF, c_sWhF, s_biF, s_bhF,
          nullptr, nullptr, nullptr, nullptr, nullptr, nullptr, nullptr,
          tkb, emb, t, 256);
    }
    ln_rows<<<(T * c) / 4, 256, 0, stream>>>(y1, s_lnF_g, s_lnF_b, T * c, 256);
    for (int i = 0; i < T; i++) {
      int tb = T - 1 - i;
      gru_step<<<dim3(c / 4, 2), 256, 0, stream>>>(
          y1 + (size_t)i * cH,  i ? hf + (size_t)(i - 1) * cH : nullptr,  hf + (size_t)i * cH,
          c_sWif, c_sWhf, s_bi_f, s_bh_f,
          y1 + (size_t)tb * cH, i ? hb + (size_t)(tb + 1) * cH : nullptr, hb + (size_t)tb * cH,
          c_sWib, c_sWhb, s_bi_b, s_bh_b,
          nullptr, nullptr, 0, 256);
    }
    sent_tail<<<c / 16, 256, 0, stream>>>(hf, hb, s_ln_g, s_ln_b, c_linW, s_linb,
                                          store, c, base);
  }

  // ---- document encoder: xw GEMMs + persistent GRUs ----
  xw_gemm<<<dim3(2304, 1), 256, 0, stream>>>(store, c_dWiF, dbiF, xw_u,
                                             nullptr, nullptr, nullptr);
  doc_gru<<<dim3(1), 1024, 0, stream>>>(xw_u, c_dWhF, dbhF,
                                        nullptr, nullptr, nullptr,
                                        yd1ln, 256, d_lnF_g, d_lnF_b, S);
  xw_gemm<<<dim3(2304, 2), 256, 0, stream>>>(yd1ln, c_dWif, dbi_f, xw_f,
                                             c_dWib, dbi_b, xw_b);
  doc_gru<<<dim3(2), 1024, 0, stream>>>(xw_f, c_dWhf, dbh_f,
                                        xw_b, c_dWhb, dbh_b,
                                        ybid, 512, nullptr, nullptr, S);
  ln_out_head<<<768, 256, 0, stream>>>(ybid, d_ln_g, d_ln_b, out_W, out_b,
                                       (float*)d_out);
}

// Round 5
// 4461.692 us; speedup vs baseline: 1.7506x; 1.7506x over previous
//
#include <hip/hip_runtime.h>

// ---------------------------------------------------------------------------
// SequenceTaggle: hierarchical GRU (sentence enc -> doc enc) on MI355X.
// V=32000 E=256 H=256 O=2 S=96 T=32 B=32, N = S*B = 3072.
// DEVICE DTYPES: float tensors f32; tokens int32; output f32.
// Internal: bf16 MFMA, f32 accumulation. Weights + emb converted to bf16 once.
// ---------------------------------------------------------------------------

typedef __bf16 bf16;
typedef __bf16 bf16x8 __attribute__((ext_vector_type(8)));
typedef __bf16 bf16x4 __attribute__((ext_vector_type(4)));
typedef float  f32x4  __attribute__((ext_vector_type(4)));

static __device__ __forceinline__ f32x4 mfma16(bf16x8 a, bf16x8 b, f32x4 c) {
  // A: lane row = lane&15, k = (lane>>4)*8 + j ; B: lane col = lane&15, same k
  // D: col = lane&15, row = (lane>>4)*4 + reg
  return __builtin_amdgcn_mfma_f32_16x16x32_bf16(a, b, c, 0, 0, 0);
}
static __device__ __forceinline__ float sigm(float x) { return 1.f / (1.f + __expf(-x)); }

// ---- generic f32 -> bf16 (n4 float4 groups) ----
__global__ __launch_bounds__(256) void cvt_bf16(
    const float* __restrict__ s, bf16* __restrict__ d, int n4)
{
  int i = blockIdx.x * 256 + threadIdx.x;
  if (i < n4) {
    float4 v = ((const float4*)s)[i];
    bf16x4 o;
    o[0] = (bf16)v.x; o[1] = (bf16)v.y; o[2] = (bf16)v.z; o[3] = (bf16)v.w;
    ((bf16x4*)d)[i] = o;
  }
}

// ---- one-shot weight conversion: 12 GRU mats (196608 ea) + linW (131072) ----
__global__ __launch_bounds__(256) void conv13(
    const float* s0, const float* s1, const float* s2, const float* s3,
    const float* s4, const float* s5, const float* s6, const float* s7,
    const float* s8, const float* s9, const float* s10, const float* s11,
    const float* s12, bf16* __restrict__ dst)
{
  const float* srcs[13] = {s0,s1,s2,s3,s4,s5,s6,s7,s8,s9,s10,s11,s12};
  int m = blockIdx.y;
  int n4 = (m == 12) ? 32768 : 49152;
  int i = blockIdx.x * 256 + threadIdx.x;
  if (i >= n4) return;
  float4 v = ((const float4*)srcs[m])[i];
  bf16x4 o;
  o[0] = (bf16)v.x; o[1] = (bf16)v.y; o[2] = (bf16)v.z; o[3] = (bf16)v.w;
  ((bf16x4*)(dst + (size_t)m * 196608))[i] = o;
}

// ---------------------------------------------------------------------------
// Fused GRU step v2 (sentence). Wave = one 16-col tile x TWO 16-row tiles
// (weights loaded once per wave, reused for both row tiles -> halves L2
// traffic). Accumulators: r,z shared across x/h paths; n kept split.
// x==nullptr -> gather from pre-converted bf16 emb via tok.
// Grid: dim3(c/8, ndir), 256 thr. wave -> col tile = wv&15, rows = (wv>>4)*32.
// ---------------------------------------------------------------------------
__global__ __launch_bounds__(256, 2) void gru_step(
    const bf16* __restrict__ xF, const bf16* __restrict__ hpF, bf16* __restrict__ hoF,
    const bf16* __restrict__ WiF, const bf16* __restrict__ WhF,
    const float* __restrict__ biF, const float* __restrict__ bhF,
    const bf16* __restrict__ xB, const bf16* __restrict__ hpB, bf16* __restrict__ hoB,
    const bf16* __restrict__ WiB, const bf16* __restrict__ WhB,
    const float* __restrict__ biB, const float* __restrict__ bhB,
    const int* __restrict__ tok, const bf16* __restrict__ embb, int t, int hstride)
{
  const bf16 *x, *hp, *Wi, *Wh;
  const float *bi, *bh;
  bf16* ho;
  if (blockIdx.y == 0) { x = xF; hp = hpF; ho = hoF; Wi = WiF; Wh = WhF; bi = biF; bh = bhF; }
  else                 { x = xB; hp = hpB; ho = hoB; Wi = WiB; Wh = WhB; bi = biB; bh = bhB; }

  int wv   = (threadIdx.x >> 6) + (blockIdx.x << 2);
  int cj   = (wv & 15) << 4;     // hidden column tile base
  int m0   = (wv >> 4) << 5;     // 32-row base (two 16-row tiles)
  int lane = threadIdx.x & 63;
  int r16  = lane & 15, g4 = lane >> 4;

  const bf16 *xp0, *xp1;
  if (x) {
    xp0 = x + (size_t)(m0 + r16) * 256;
    xp1 = xp0 + (size_t)16 * 256;
  } else {
    int n0 = m0 + r16, n1 = n0 + 16;
    int tk0 = tok[((n0 >> 5) << 10) + (t << 5) + (n0 & 31)];
    int tk1 = tok[((n1 >> 5) << 10) + (t << 5) + (n1 & 31)];
    xp0 = embb + (size_t)tk0 * 256;
    xp1 = embb + (size_t)tk1 * 256;
  }
  const bf16* wi = Wi + (size_t)(cj + r16) * 256;   // r rows; z +65536, n +131072
  const bf16* wh = Wh + (size_t)(cj + r16) * 256;

  f32x4 Ar0 = {0,0,0,0}, Ar1 = {0,0,0,0};   // r gate (x+h combined)
  f32x4 Az0 = {0,0,0,0}, Az1 = {0,0,0,0};   // z gate (x+h combined)
  f32x4 Xn0 = {0,0,0,0}, Xn1 = {0,0,0,0};   // n gate, x part
  f32x4 Hn0 = {0,0,0,0}, Hn1 = {0,0,0,0};   // n gate, h part

#pragma unroll
  for (int kk = 0; kk < 8; kk++) {
    int k0 = kk * 32 + g4 * 8;
    bf16x8 a0 = *(const bf16x8*)(xp0 + k0);
    bf16x8 a1 = *(const bf16x8*)(xp1 + k0);
    bf16x8 wr = *(const bf16x8*)(wi + k0);
    bf16x8 wz = *(const bf16x8*)(wi + 65536 + k0);
    bf16x8 wn = *(const bf16x8*)(wi + 131072 + k0);
    Ar0 = mfma16(a0, wr, Ar0); Ar1 = mfma16(a1, wr, Ar1);
    Az0 = mfma16(a0, wz, Az0); Az1 = mfma16(a1, wz, Az1);
    Xn0 = mfma16(a0, wn, Xn0); Xn1 = mfma16(a1, wn, Xn1);
  }
  if (hp) {
    const bf16* hq0 = hp + (size_t)(m0 + r16) * hstride;
    const bf16* hq1 = hq0 + (size_t)16 * hstride;
#pragma unroll
    for (int kk = 0; kk < 8; kk++) {
      int k0 = kk * 32 + g4 * 8;
      bf16x8 a0 = *(const bf16x8*)(hq0 + k0);
      bf16x8 a1 = *(const bf16x8*)(hq1 + k0);
      bf16x8 wr = *(const bf16x8*)(wh + k0);
      bf16x8 wz = *(const bf16x8*)(wh + 65536 + k0);
      bf16x8 wn = *(const bf16x8*)(wh + 131072 + k0);
      Ar0 = mfma16(a0, wr, Ar0); Ar1 = mfma16(a1, wr, Ar1);
      Az0 = mfma16(a0, wz, Az0); Az1 = mfma16(a1, wz, Az1);
      Hn0 = mfma16(a0, wn, Hn0); Hn1 = mfma16(a1, wn, Hn1);
    }
  }

  float br = bi[cj + r16] + bh[cj + r16];
  float bz = bi[256 + cj + r16] + bh[256 + cj + r16];
  float bin = bi[512 + cj + r16], bhn = bh[512 + cj + r16];

#pragma unroll
  for (int rt = 0; rt < 2; rt++) {
    f32x4 Ar = rt ? Ar1 : Ar0, Az = rt ? Az1 : Az0;
    f32x4 Xn = rt ? Xn1 : Xn0, Hn = rt ? Hn1 : Hn0;
#pragma unroll
    for (int j = 0; j < 4; j++) {
      int orow = m0 + rt * 16 + g4 * 4 + j;
      float r = sigm(Ar[j] + br);
      float z = sigm(Az[j] + bz);
      float n = tanhf(Xn[j] + bin + r * (Hn[j] + bhn));
      float hpv = hp ? (float)hp[(size_t)orow * hstride + cj + r16] : 0.f;
      ho[(size_t)orow * hstride + cj + r16] = (bf16)((1.f - z) * n + z * hpv);
    }
  }
}

// ---------------------------------------------------------------------------
// Row LayerNorm in place (bf16 data, f32 params), wave per row. D in {256,512}.
// ---------------------------------------------------------------------------
__global__ __launch_bounds__(256) void ln_rows(
    bf16* __restrict__ data, const float* __restrict__ gam, const float* __restrict__ bet,
    int rows, int D)
{
  int wid = threadIdx.x >> 6, lane = threadIdx.x & 63;
  int row = (blockIdx.x << 2) + wid;
  if (row >= rows) return;
  bf16* p = data + (size_t)row * D;
  int c = D >> 6;
  float v[8];
  float s = 0.f;
  if (c == 8) {
    bf16x8 t8 = *(const bf16x8*)(p + lane * 8);
#pragma unroll
    for (int j = 0; j < 8; j++) { v[j] = (float)t8[j]; s += v[j]; }
  } else {
    bf16x4 t4 = *(const bf16x4*)(p + lane * 4);
#pragma unroll
    for (int j = 0; j < 4; j++) { v[j] = (float)t4[j]; s += v[j]; }
#pragma unroll
    for (int j = 4; j < 8; j++) v[j] = 0.f;
  }
  float sq = 0.f;
  for (int j = 0; j < c; j++) sq += v[j] * v[j];
  for (int m = 32; m; m >>= 1) { s += __shfl_xor(s, m); sq += __shfl_xor(sq, m); }
  float invD = 1.f / (float)D;
  float mu  = s * invD;
  float var = sq * invD - mu * mu;
  float inv = rsqrtf(fmaxf(var, 0.f) + 1e-5f);
  int base = lane * c;
  for (int j = 0; j < c; j++) {
    float o = (v[j] - mu) * inv * gam[base + j] + bet[base + j];
    p[base + j] = (bf16)o;
  }
}

// ---------------------------------------------------------------------------
// Fused sentence tail (round-3 verified form).
// ---------------------------------------------------------------------------
__global__ __launch_bounds__(256) void sent_tail(
    const bf16* __restrict__ hf, const bf16* __restrict__ hb,
    const float* __restrict__ gam, const float* __restrict__ bet,
    const bf16* __restrict__ W, const float* __restrict__ bias,
    bf16* __restrict__ store, int c, int row_base)
{
  int wave = threadIdx.x >> 6;
  int lane = threadIdx.x & 63;
  int r16 = lane & 15, g4 = lane >> 4;
  int r0 = (int)blockIdx.x << 4;
  size_t rowoff = (size_t)(r0 + r16) * 256;

  f32x4 ms0 = {0,0,0,0}, ms1 = {0,0,0,0}, ms2 = {0,0,0,0}, ms3 = {0,0,0,0};

  for (int t = 0; t < 32; t++) {
    const bf16* pf = hf + (size_t)t * c * 256 + rowoff;
    const bf16* pb = hb + (size_t)t * c * 256 + rowoff;
    bf16x8 xv[16];
    float s = 0.f, sq = 0.f;
#pragma unroll
    for (int kk = 0; kk < 16; kk++) {
      int k0 = kk * 32 + g4 * 8;
      xv[kk] = (kk < 8) ? *(const bf16x8*)(pf + k0) : *(const bf16x8*)(pb + k0 - 256);
#pragma unroll
      for (int j = 0; j < 8; j++) { float f = (float)xv[kk][j]; s += f; sq += f * f; }
    }
    s  += __shfl_xor(s, 16);  s  += __shfl_xor(s, 32);
    sq += __shfl_xor(sq, 16); sq += __shfl_xor(sq, 32);
    float mu  = s * (1.f / 512.f);
    float var = sq * (1.f / 512.f) - mu * mu;
    float inv = rsqrtf(fmaxf(var, 0.f) + 1e-5f);
#pragma unroll
    for (int kk = 0; kk < 16; kk++) {
      int k0 = kk * 32 + g4 * 8;
      float ga[8], be[8];
      *(float4*)(ga)     = *(const float4*)(gam + k0);
      *(float4*)(ga + 4) = *(const float4*)(gam + k0 + 4);
      *(float4*)(be)     = *(const float4*)(bet + k0);
      *(float4*)(be + 4) = *(const float4*)(bet + k0 + 4);
#pragma unroll
      for (int j = 0; j < 8; j++)
        xv[kk][j] = (bf16)(((float)xv[kk][j] - mu) * inv * ga[j] + be[j]);
    }
#pragma unroll
    for (int tc = 0; tc < 4; tc++) {
      int cj = wave * 64 + tc * 16;
      const bf16* wp = W + (size_t)(cj + r16) * 512;
      f32x4 acc = {0,0,0,0};
#pragma unroll
      for (int kk = 0; kk < 16; kk++)
        acc = mfma16(xv[kk], *(const bf16x8*)(wp + kk * 32 + g4 * 8), acc);
      float bb = bias[cj + r16];
      f32x4* msp = (tc == 0) ? &ms0 : (tc == 1) ? &ms1 : (tc == 2) ? &ms2 : &ms3;
#pragma unroll
      for (int j = 0; j < 4; j++) (*msp)[j] += tanhf(acc[j] + bb);
    }
  }
#pragma unroll
  for (int tc = 0; tc < 4; tc++) {
    int cj = wave * 64 + tc * 16;
    f32x4 ms = (tc == 0) ? ms0 : (tc == 1) ? ms1 : (tc == 2) ? ms2 : ms3;
#pragma unroll
    for (int j = 0; j < 4; j++) {
      int row = row_base + r0 + g4 * 4 + j;
      store[(size_t)row * 256 + cj + r16] = (bf16)(ms[j] * 0.03125f);
    }
  }
}

// ---------------------------------------------------------------------------
// xw = X(M x 256 bf16) @ W(768 x 256 bf16)^T + bias(f32) -> (M x 768) bf16.
// gridDim.y selects (W0,b0,o0) / (W1,b1,o1). blocks = M/16*48/4.
// ---------------------------------------------------------------------------
__global__ __launch_bounds__(256) void xw_gemm(
    const bf16* __restrict__ X,
    const bf16* __restrict__ W0, const float* __restrict__ b0, bf16* __restrict__ o0,
    const bf16* __restrict__ W1, const float* __restrict__ b1, bf16* __restrict__ o1)
{
  const bf16* W = blockIdx.y ? W1 : W0;
  const float* bias = blockIdx.y ? b1 : b0;
  bf16* out = blockIdx.y ? o1 : o0;
  int wave = (int)blockIdx.x * 4 + (threadIdx.x >> 6);
  int rt = wave / 48, ct = wave - rt * 48;
  int lane = threadIdx.x & 63;
  int r16 = lane & 15, g4 = lane >> 4;
  const bf16* ap = X + (size_t)(rt * 16 + r16) * 256;
  const bf16* wp = W + (size_t)(ct * 16 + r16) * 256;
  f32x4 acc = {0,0,0,0};
#pragma unroll
  for (int kk = 0; kk < 8; kk++) {
    int k0 = kk * 32 + g4 * 8;
    acc = mfma16(*(const bf16x8*)(ap + k0), *(const bf16x8*)(wp + k0), acc);
  }
  float bv = bias[ct * 16 + r16];
#pragma unroll
  for (int j = 0; j < 4; j++)
    out[(size_t)(rt * 16 + g4 * 4 + j) * 768 + ct * 16 + r16] = (bf16)(acc[j] + bv);
}

// ---------------------------------------------------------------------------
// Persistent doc GRU v2: 1024 thr = 16 waves; wave w owns col tile w (16 cols),
// BOTH 16-row tiles (weights loaded once). h (32x256) in padded LDS.
// xw (bf16, precomputed xW+bi) prefetched to regs at step top -> remote-L2
// latency hidden under the MFMA phase. blockIdx.x = direction.
// ---------------------------------------------------------------------------
__global__ __launch_bounds__(1024, 4) void doc_gru(
    const bf16* __restrict__ xwF, const bf16* __restrict__ WhF_, const float* __restrict__ bhF_,
    const bf16* __restrict__ xwB, const bf16* __restrict__ WhB_, const float* __restrict__ bhB_,
    bf16* __restrict__ yout, int ostride,
    const float* __restrict__ lng, const float* __restrict__ lnb, int S)
{
  int dir = blockIdx.x;
  const bf16*  xw = dir ? xwB : xwF;
  const bf16*  Wh = dir ? WhB_ : WhF_;
  const float* bh = dir ? bhB_ : bhF_;
  int obase = dir ? 256 : 0;

  __shared__ bf16 hbuf[32][264];   // +8 pad: balanced banks for b128 frag reads
  for (int idx = threadIdx.x; idx < 32 * 264; idx += 1024) ((bf16*)hbuf)[idx] = (bf16)0.f;
  __syncthreads();

  int w = threadIdx.x >> 6, lane = threadIdx.x & 63;
  int r16 = lane & 15, g4 = lane >> 4;
  int c = w * 16 + r16;
  const bf16* whp = Wh + (size_t)c * 256;
  float bhr = bh[c], bhz = bh[c + 256], bhn = bh[c + 512];

  for (int i = 0; i < S; i++) {
    int st = dir ? (S - 1 - i) : i;
    // 1) prefetch xw for this step (remote; consumed after MFMA phase)
    const bf16* xp = xw + (size_t)st * 24576;   // 32*768
    float xr[2][3][4];
#pragma unroll
    for (int rt = 0; rt < 2; rt++)
#pragma unroll
      for (int j = 0; j < 4; j++) {
        const bf16* q = xp + (size_t)(rt * 16 + g4 * 4 + j) * 768 + c;
        xr[rt][0][j] = (float)q[0];
        xr[rt][1][j] = (float)q[256];
        xr[rt][2][j] = (float)q[512];
      }
    // 2) h_prev for the blend
    float hp0[4], hp1[4];
#pragma unroll
    for (int j = 0; j < 4; j++) {
      hp0[j] = (float)hbuf[g4 * 4 + j][c];
      hp1[j] = (float)hbuf[16 + g4 * 4 + j][c];
    }
    // 3) h @ Wh via MFMA, both row tiles share the weight fragments
    f32x4 A00 = {0,0,0,0}, A01 = {0,0,0,0}, A02 = {0,0,0,0};
    f32x4 A10 = {0,0,0,0}, A11 = {0,0,0,0}, A12 = {0,0,0,0};
#pragma unroll
    for (int kk = 0; kk < 8; kk++) {
      int k0 = kk * 32 + g4 * 8;
      bf16x8 a0 = *(const bf16x8*)&hbuf[r16][k0];
      bf16x8 a1 = *(const bf16x8*)&hbuf[16 + r16][k0];
      bf16x8 w0 = *(const bf16x8*)(whp + k0);
      bf16x8 w1 = *(const bf16x8*)(whp + 65536 + k0);
      bf16x8 w2 = *(const bf16x8*)(whp + 131072 + k0);
      A00 = mfma16(a0, w0, A00); A10 = mfma16(a1, w0, A10);
      A01 = mfma16(a0, w1, A01); A11 = mfma16(a1, w1, A11);
      A02 = mfma16(a0, w2, A02); A12 = mfma16(a1, w2, A12);
    }
    // 4) gates
    float hnew[2][4];
#pragma unroll
    for (int rt = 0; rt < 2; rt++) {
      f32x4 A0 = rt ? A10 : A00, A1 = rt ? A11 : A01, A2 = rt ? A12 : A02;
#pragma unroll
      for (int j = 0; j < 4; j++) {
        float r = sigm(xr[rt][0][j] + A0[j] + bhr);
        float z = sigm(xr[rt][1][j] + A1[j] + bhz);
        float n = tanhf(xr[rt][2][j] + r * (A2[j] + bhn));
        float hpv = rt ? hp1[j] : hp0[j];
        hnew[rt][j] = (1.f - z) * n + z * hpv;
      }
    }
    __syncthreads();               // all hbuf reads done
#pragma unroll
    for (int rt = 0; rt < 2; rt++)
#pragma unroll
      for (int j = 0; j < 4; j++)
        hbuf[rt * 16 + g4 * 4 + j][c] = (bf16)hnew[rt][j];
    __syncthreads();               // h_t visible
    // 5) output
    if (lng) {
      // fused LN(256) on y; recurrence keeps raw h. wave -> rows w*2, w*2+1
#pragma unroll
      for (int rr = 0; rr < 2; rr++) {
        int row = w * 2 + rr;
        bf16x4 v4 = *(const bf16x4*)&hbuf[row][lane * 4];
        float v[4]; float sm = 0.f, sq = 0.f;
#pragma unroll
        for (int j = 0; j < 4; j++) { v[j] = (float)v4[j]; sm += v[j]; sq += v[j] * v[j]; }
        for (int msk = 32; msk; msk >>= 1) { sm += __shfl_xor(sm, msk); sq += __shfl_xor(sq, msk); }
        float mu  = sm * (1.f / 256.f);
        float var = sq * (1.f / 256.f) - mu * mu;
        float inv = rsqrtf(fmaxf(var, 0.f) + 1e-5f);
        bf16x4 o;
#pragma unroll
        for (int j = 0; j < 4; j++)
          o[j] = (bf16)((v[j] - mu) * inv * lng[lane * 4 + j] + lnb[lane * 4 + j]);
        *(bf16x4*)&yout[((size_t)st * 32 + row) * ostride + lane * 4] = o;
      }
    } else {
#pragma unroll
      for (int rt = 0; rt < 2; rt++)
#pragma unroll
        for (int j = 0; j < 4; j++)
          yout[((size_t)st * 32 + rt * 16 + g4 * 4 + j) * ostride + obase + c] = (bf16)hnew[rt][j];
    }
  }
}

// ---------------------------------------------------------------------------
// Fused LN(512) + sigmoid head: out(3072x2 f32). Wave per row.
// ---------------------------------------------------------------------------
__global__ __launch_bounds__(256) void ln_out_head(
    const bf16* __restrict__ X, const float* __restrict__ lng, const float* __restrict__ lnb,
    const float* __restrict__ W, const float* __restrict__ bias, float* __restrict__ out)
{
  int w = threadIdx.x >> 6, lane = threadIdx.x & 63;
  int row = (int)blockIdx.x * 4 + w;
  bf16x8 v8 = *(const bf16x8*)&X[(size_t)row * 512 + lane * 8];
  float v[8]; float sm = 0.f, sq = 0.f;
#pragma unroll
  for (int j = 0; j < 8; j++) { v[j] = (float)v8[j]; sm += v[j]; sq += v[j] * v[j]; }
  for (int msk = 32; msk; msk >>= 1) { sm += __shfl_xor(sm, msk); sq += __shfl_xor(sq, msk); }
  float mu  = sm * (1.f / 512.f);
  float var = sq * (1.f / 512.f) - mu * mu;
  float inv = rsqrtf(fmaxf(var, 0.f) + 1e-5f);
  float a0 = 0.f, a1 = 0.f;
  int base = lane * 8;
#pragma unroll
  for (int j = 0; j < 8; j++) {
    float y = (v[j] - mu) * inv * lng[base + j] + lnb[base + j];
    a0 += y * W[base + j];
    a1 += y * W[512 + base + j];
  }
  for (int msk = 32; msk; msk >>= 1) { a0 += __shfl_xor(a0, msk); a1 += __shfl_xor(a1, msk); }
  if (lane == 0) {
    out[(size_t)row * 2 + 0] = sigm(a0 + bias[0]);
    out[(size_t)row * 2 + 1] = sigm(a1 + bias[1]);
  }
}

// ---------------------------------------------------------------------------
extern "C" void kernel_launch(void* const* d_in, const int* in_sizes, int n_in,
                              void* d_out, int out_size, void* d_ws, size_t ws_size,
                              hipStream_t stream)
{
  (void)in_sizes; (void)n_in; (void)out_size;
  const int*   tokens = (const int*)d_in[0];
  const float* emb    = (const float*)d_in[1];
  auto fp = [&](int i) { return (const float*)d_in[i]; };
  const float *s_WiF = fp(2),  *s_WhF = fp(3),  *s_biF = fp(4),  *s_bhF = fp(5);
  const float *s_lnF_g = fp(6), *s_lnF_b = fp(7);
  const float *s_Wi_f = fp(8),  *s_Wh_f = fp(9),  *s_bi_f = fp(10), *s_bh_f = fp(11);
  const float *s_Wi_b = fp(12), *s_Wh_b = fp(13), *s_bi_b = fp(14), *s_bh_b = fp(15);
  const float *s_ln_g = fp(16), *s_ln_b = fp(17), *s_linW = fp(18), *s_linb = fp(19);
  const float *dWiF = fp(20), *dWhF = fp(21), *dbiF = fp(22), *dbhF = fp(23);
  const float *d_lnF_g = fp(24), *d_lnF_b = fp(25);
  const float *dWi_f = fp(26), *dWh_f = fp(27), *dbi_f = fp(28), *dbh_f = fp(29);
  const float *dWi_b = fp(30), *dWh_b = fp(31), *dbi_b = fp(32), *dbh_b = fp(33);
  const float *d_ln_g = fp(34), *d_ln_b = fp(35), *out_W = fp(36), *out_b = fp(37);

  const int T = 32, S = 96;
  const int GW = 196608;           // 768*256 elems per GRU weight matrix

  // ---- converted bf16 weights + emb ----
  bf16* wc = (bf16*)d_ws;
  bf16 *c_sWiF = wc,         *c_sWhF = wc + GW;
  bf16 *c_sWif = wc + 2*GW,  *c_sWhf = wc + 3*GW;
  bf16 *c_sWib = wc + 4*GW,  *c_sWhb = wc + 5*GW;
  bf16 *c_dWiF = wc + 6*GW,  *c_dWhF = wc + 7*GW;
  bf16 *c_dWif = wc + 8*GW,  *c_dWhf = wc + 9*GW;
  bf16 *c_dWib = wc + 10*GW, *c_dWhb = wc + 11*GW;
  bf16 *c_linW = wc + 12*GW;
  const size_t WB = (size_t)(12 * GW + 131072) * 2;       // 4,980,736 B
  bf16* embb = (bf16*)((char*)d_ws + WB);                  // 32000x256 bf16
  const size_t EB = (size_t)32000 * 256 * 2;               // 16,384,000 B

  conv13<<<dim3(192, 13), 256, 0, stream>>>(
      s_WiF, s_WhF, s_Wi_f, s_Wh_f, s_Wi_b, s_Wh_b,
      dWiF, dWhF, dWi_f, dWh_f, dWi_b, dWh_b, s_linW, wc);
  cvt_bf16<<<8000, 256, 0, stream>>>(emb, embb, 2048000);

  // ---- fixed workspace: xw bufs (bf16) + doc buffers ----
  char* ws = (char*)d_ws + WB + EB;
  bf16* xw_u = (bf16*)ws;                            // (3072, 768)
  bf16* xw_f = xw_u + (size_t)3072 * 768;
  bf16* xw_b = xw_f + (size_t)3072 * 768;
  bf16* store = xw_b + (size_t)3072 * 768;           // (3072, 256)
  bf16* yd1ln = store + (size_t)3072 * 256;          // (3072, 256) LN'd
  bf16* ybid  = yd1ln + (size_t)3072 * 256;          // (3072, 512) f|b
  const size_t fixedB = WB + EB + ((size_t)3 * 3072 * 768
                      + (size_t)3072 * 256 * 2 + (size_t)3072 * 512) * 2;

  // ---- sentence chunk size (rows; multiple of 32 = whole sentences) ----
  int c = 3072;
  while (c > 96 && fixedB + (size_t)3 * T * c * 512 > ws_size) c >>= 1;
  bf16* y1 = (bf16*)((char*)d_ws + fixedB);          // (T, c, 256)
  bf16* hf = y1 + (size_t)T * c * 256;
  bf16* hb = hf + (size_t)T * c * 256;
  const size_t cH = (size_t)c * 256;

  // ---- sentence encoder, chunked ----
  for (int base = 0; base < 3072; base += c) {
    const int* tkb = tokens + (size_t)base * 32;
    for (int t = 0; t < T; t++) {
      gru_step<<<dim3(c / 8, 1), 256, 0, stream>>>(
          nullptr, t ? y1 + (size_t)(t - 1) * cH : nullptr, y1 + (size_t)t * cH,
          c_sWiF, c_sWhF, s_biF, s_bhF,
          nullptr, nullptr, nullptr, nullptr, nullptr, nullptr, nullptr,
          tkb, embb, t, 256);
    }
    ln_rows<<<(T * c) / 4, 256, 0, stream>>>(y1, s_lnF_g, s_lnF_b, T * c, 256);
    for (int i = 0; i < T; i++) {
      int tb = T - 1 - i;
      gru_step<<<dim3(c / 8, 2), 256, 0, stream>>>(
          y1 + (size_t)i * cH,  i ? hf + (size_t)(i - 1) * cH : nullptr,  hf + (size_t)i * cH,
          c_sWif, c_sWhf, s_bi_f, s_bh_f,
          y1 + (size_t)tb * cH, i ? hb + (size_t)(tb + 1) * cH : nullptr, hb + (size_t)tb * cH,
          c_sWib, c_sWhb, s_bi_b, s_bh_b,
          nullptr, nullptr, 0, 256);
    }
    sent_tail<<<c / 16, 256, 0, stream>>>(hf, hb, s_ln_g, s_ln_b, c_linW, s_linb,
                                          store, c, base);
  }

  // ---- document encoder: xw GEMMs + persistent GRUs ----
  xw_gemm<<<dim3(2304, 1), 256, 0, stream>>>(store, c_dWiF, dbiF, xw_u,
                                             nullptr, nullptr, nullptr);
  doc_gru<<<dim3(1), 1024, 0, stream>>>(xw_u, c_dWhF, dbhF,
                                        nullptr, nullptr, nullptr,
                                        yd1ln, 256, d_lnF_g, d_lnF_b, S);
  xw_gemm<<<dim3(2304, 2), 256, 0, stream>>>(yd1ln, c_dWif, dbi_f, xw_f,
                                             c_dWib, dbi_b, xw_b);
  doc_gru<<<dim3(2), 1024, 0, stream>>>(xw_f, c_dWhf, dbh_f,
                                        xw_b, c_dWhb, dbh_b,
                                        ybid, 512, nullptr, nullptr, S);
  ln_out_head<<<768, 256, 0, stream>>>(ybid, d_ln_g, d_ln_b, out_W, out_b,
                                       (float*)d_out);
}